// Round 5
// baseline (722.755 us; speedup 1.0000x reference)
//
#include <hip/hip_runtime.h>
#include <hip/hip_bf16.h>
#include <math.h>

#define N_NODES 20000
#define N_EDGES 320000
#define NODE_DIM 64
#define EDGE_DIM 32
#define HID 128
#define HEADS 4
#define HC1 512   // HEADS*HID
#define NEG_SLOPE 0.2f

__device__ __forceinline__ unsigned short f2b(float f) {
  unsigned u = __float_as_uint(f);
  unsigned r = (u + 0x7fffu + ((u >> 16) & 1u)) >> 16;
  return (unsigned short)r;
}
__device__ __forceinline__ float b2f(unsigned short b) {
  return __uint_as_float(((unsigned)b) << 16);
}

// ---------------- CSR build + degree sort ----------------
__global__ void zero_deg_kernel(int* deg, int* hist) {
  int i = blockIdx.x * blockDim.x + threadIdx.x;
  if (i < N_NODES) deg[i] = 0;
  if (i < 64) hist[i] = 0;
}

__global__ void deg_count_kernel(const int* __restrict__ dsts, int* __restrict__ deg) {
  int e = blockIdx.x * blockDim.x + threadIdx.x;
  if (e < N_EDGES) atomicAdd(&deg[dsts[e]], 1);
}

__global__ void hist_kernel(const int* __restrict__ deg, int* __restrict__ hist) {
  int n = blockIdx.x * blockDim.x + threadIdx.x;
  if (n >= N_NODES) return;
  int k = deg[n]; k = k > 63 ? 63 : k;
  atomicAdd(&hist[63 - k], 1);           // descending degree order (LPT)
}

__global__ void histscan_kernel(const int* __restrict__ hist, int* __restrict__ cursor2) {
  int lane = threadIdx.x;                 // 64 threads
  int v = hist[lane];
  int s = v;
  #pragma unroll
  for (int o = 1; o < 64; o <<= 1) { int u = __shfl_up(s, o); if (lane >= o) s += u; }
  cursor2[lane] = s - v;                  // exclusive prefix
}

__global__ void permscatter_kernel(const int* __restrict__ deg, int* __restrict__ cursor2,
                                   int* __restrict__ perm) {
  int n = blockIdx.x * blockDim.x + threadIdx.x;
  if (n >= N_NODES) return;
  int k = deg[n]; k = k > 63 ? 63 : k;
  int pos = atomicAdd(&cursor2[63 - k], 1);
  perm[pos] = n;
}

__global__ __launch_bounds__(1024) void scan_kernel(
    const int* __restrict__ deg, int* __restrict__ offs, int* __restrict__ cursor)
{
  __shared__ int part[1024];
  int t = threadIdx.x;
  const int C = 20;                 // 1024*20 = 20480 >= N_NODES
  int base = t * C;
  int loc[C]; int s = 0;
  #pragma unroll
  for (int i = 0; i < C; i++) { loc[i] = s; int idx = base + i; s += (idx < N_NODES) ? deg[idx] : 0; }
  part[t] = s;
  __syncthreads();
  for (int off = 1; off < 1024; off <<= 1) {
    int v = (t >= off) ? part[t - off] : 0;
    __syncthreads();
    part[t] += v;
    __syncthreads();
  }
  int pbase = (t > 0) ? part[t - 1] : 0;
  #pragma unroll
  for (int i = 0; i < C; i++) {
    int idx = base + i;
    if (idx < N_NODES) { int o = pbase + loc[i]; offs[idx] = o; cursor[idx] = o; }
  }
  if (t == 1023) offs[N_NODES] = part[1023];
}

__global__ void scatter_kernel(const int* __restrict__ dsts, int* __restrict__ cursor,
                               int* __restrict__ csr) {
  int e = blockIdx.x * blockDim.x + threadIdx.x;
  if (e >= N_EDGES) return;
  int pos = atomicAdd(&cursor[dsts[e]], 1);
  csr[pos] = e;
}

// ---------------- linear1 ----------------
__global__ __launch_bounds__(256) void linear1_kernel(
    const float* __restrict__ x, const float* __restrict__ Wl,
    const float* __restrict__ bl, const float* __restrict__ Wr,
    const float* __restrict__ br, float* __restrict__ xl, float* __restrict__ xr)
{
  __shared__ float xsT[NODE_DIM][16];
  int n0 = blockIdx.x * 16;
  int t = threadIdx.x;
  {
    int flat = t * 4;
    int i = flat >> 6, k = flat & 63;
    float4 v = *(const float4*)&x[(size_t)(n0 + i) * NODE_DIM + k];
    xsT[k + 0][i] = v.x; xsT[k + 1][i] = v.y; xsT[k + 2][i] = v.z; xsT[k + 3][i] = v.w;
  }
  __syncthreads();
  for (int m = 0; m < 2; m++) {
    const float* W  = m ? Wr : Wl;
    const float* bb = m ? br : bl;
    float* out = m ? xr : xl;
    for (int jh = 0; jh < 2; jh++) {
      int j = t + jh * 256;
      float acc[16];
      #pragma unroll
      for (int i = 0; i < 16; i++) acc[i] = 0.f;
      for (int k = 0; k < NODE_DIM; k++) {
        float w = W[k * HC1 + j];
        float xv[16];
        *(float4*)&xv[0]  = *(const float4*)&xsT[k][0];
        *(float4*)&xv[4]  = *(const float4*)&xsT[k][4];
        *(float4*)&xv[8]  = *(const float4*)&xsT[k][8];
        *(float4*)&xv[12] = *(const float4*)&xsT[k][12];
        #pragma unroll
        for (int i = 0; i < 16; i++) acc[i] = fmaf(xv[i], w, acc[i]);
      }
      float bj = bb[j];
      #pragma unroll
      for (int i = 0; i < 16; i++) out[(size_t)(n0 + i) * HC1 + j] = acc[i] + bj;
    }
  }
}

// ---------------- fused layer 1 ----------------
// block = 512 threads = 8 waves = 8 nodes (degree-sorted via perm) sharing Ws.
// Chunk ea rows staged in per-wave LDS (coalesced), GEMM reads broadcast ds_read.
template<bool H1BF>
__global__ __launch_bounds__(512, 2) void fused1_kernel(
    const float* __restrict__ ea, const int* __restrict__ srcs,
    const float* __restrict__ We, const float* __restrict__ att,
    const float* __restrict__ xl, const float* __restrict__ xr,
    const float* __restrict__ bias, const int* __restrict__ offs,
    const int* __restrict__ csr, const int* __restrict__ perm,
    void* __restrict__ h1out)
{
  __shared__ float Ws[EDGE_DIM * HC1];     // 64KB
  __shared__ float eas[8][4][EDGE_DIM];    // 4KB, per-wave chunk ea tile
  int t = threadIdx.x;
  for (int i = t * 4; i < EDGE_DIM * HC1; i += 2048)
    *(float4*)&Ws[i] = *(const float4*)&We[i];
  __syncthreads();
  int wave = t >> 6, lane = t & 63;
  int n = perm[blockIdx.x * 8 + wave];     // 2500*8 = 20000 exact
  int ca = lane * 4;                       // group A channels
  int cb = 256 + lane * 4;                 // group B channels
  float atA[4], atB[4], xrA[4], xrB[4];
  *(float4*)atA = *(const float4*)&att[ca];
  *(float4*)atB = *(const float4*)&att[cb];
  *(float4*)xrA = *(const float4*)&xr[(size_t)n * HC1 + ca];
  *(float4*)xrB = *(const float4*)&xr[(size_t)n * HC1 + cb];
  float oA[4] = {0.f,0.f,0.f,0.f}, oB[4] = {0.f,0.f,0.f,0.f};
  float mA = -3.0e38f, dA = 0.f, mB = -3.0e38f, dB = 0.f;
  int beg = offs[n], end = offs[n + 1];
  int ev = 0, sv = 0;
  if (lane < 4 && beg + lane < end) { ev = csr[beg + lane]; sv = srcs[ev]; }
  for (int i0 = beg; i0 < end; i0 += 4) {
    int nv = end - i0; if (nv > 4) nv = 4;
    int sarr[4];
    #pragma unroll
    for (int j = 0; j < 4; j++) sarr[j] = __shfl(sv, j);
    // stage this chunk's ea rows into per-wave LDS (coalesced float2/lane)
    {
      int mye = __shfl(ev, lane >> 4);     // lane's edge (wave groups of 16)
      float2 eav = *(const float2*)&ea[(size_t)mye * EDGE_DIM + (lane & 15) * 2];
      *(float2*)&eas[wave][lane >> 4][(lane & 15) * 2] = eav;
    }
    // xl gathers issued before GEMM (latency hidden under FMA stream)
    float xA[4][4], xB[4][4];
    #pragma unroll
    for (int j = 0; j < 4; j++) {
      if (j < nv) {
        const float* p = &xl[(size_t)sarr[j] * HC1];
        *(float4*)&xA[j][0] = *(const float4*)(p + ca);
        *(float4*)&xB[j][0] = *(const float4*)(p + cb);
      } else {
        #pragma unroll
        for (int c = 0; c < 4; c++) { xA[j][c] = 0.f; xB[j][c] = 0.f; }
      }
    }
    // prefetch next chunk's indices
    if (lane < 4 && i0 + 4 + lane < end) { ev = csr[i0 + 4 + lane]; sv = srcs[ev]; }
    // ee-GEMM: LDS-only operand reads
    float aA[4][4], aB[4][4];
    #pragma unroll
    for (int j = 0; j < 4; j++)
      #pragma unroll
      for (int c = 0; c < 4; c++) { aA[j][c] = 0.f; aB[j][c] = 0.f; }
    #pragma unroll 2
    for (int kk = 0; kk < 8; kk++) {
      float av[4][4];
      #pragma unroll
      for (int j = 0; j < 4; j++)
        *(float4*)&av[j][0] = *(const float4*)&eas[wave][j][kk * 4];
      #pragma unroll
      for (int dk = 0; dk < 4; dk++) {
        float wA[4], wB[4];
        *(float4*)wA = *(const float4*)&Ws[(kk * 4 + dk) * HC1 + ca];
        *(float4*)wB = *(const float4*)&Ws[(kk * 4 + dk) * HC1 + cb];
        #pragma unroll
        for (int j = 0; j < 4; j++) {
          float a = av[j][dk];
          #pragma unroll
          for (int c = 0; c < 4; c++) {
            aA[j][c] = fmaf(a, wA[c], aA[j][c]);
            aB[j][c] = fmaf(a, wB[c], aB[j][c]);
          }
        }
      }
    }
    // tail: logits (parallel butterflies), defer-max softmax, accumulate
    float plA[4], plB[4];
    #pragma unroll
    for (int j = 0; j < 4; j++) {
      float sA = 0.f, sB = 0.f;
      #pragma unroll
      for (int c = 0; c < 4; c++) {
        float zA = aA[j][c] + xA[j][c] + xrA[c];
        float zB = aB[j][c] + xB[j][c] + xrB[c];
        zA = zA > 0.f ? zA : NEG_SLOPE * zA;
        zB = zB > 0.f ? zB : NEG_SLOPE * zB;
        sA = fmaf(zA, atA[c], sA);
        sB = fmaf(zB, atB[c], sB);
      }
      #pragma unroll
      for (int o = 1; o <= 16; o <<= 1) {
        sA += __shfl_xor(sA, o);
        sB += __shfl_xor(sB, o);
      }
      plA[j] = (j < nv) ? sA : -3.0e38f;
      plB[j] = (j < nv) ? sB : -3.0e38f;
    }
    float cmA = fmaxf(fmaxf(plA[0], plA[1]), fmaxf(plA[2], plA[3]));
    float cmB = fmaxf(fmaxf(plB[0], plB[1]), fmaxf(plB[2], plB[3]));
    float mnA = fmaxf(mA, cmA), mnB = fmaxf(mB, cmB);
    if (__any(mnA > mA + 8.f || mnB > mB + 8.f)) {
      float fsA = __expf(mA - mnA), fsB = __expf(mB - mnB);
      dA *= fsA; dB *= fsB;
      #pragma unroll
      for (int c = 0; c < 4; c++) { oA[c] *= fsA; oB[c] *= fsB; }
      mA = mnA; mB = mnB;
    }
    float pA[4], pB[4];
    #pragma unroll
    for (int j = 0; j < 4; j++) { pA[j] = __expf(plA[j] - mA); pB[j] = __expf(plB[j] - mB); }
    dA += (pA[0] + pA[1]) + (pA[2] + pA[3]);
    dB += (pB[0] + pB[1]) + (pB[2] + pB[3]);
    #pragma unroll
    for (int c = 0; c < 4; c++) {
      oA[c] += (pA[0] * xA[0][c] + pA[1] * xA[1][c]) + (pA[2] * xA[2][c] + pA[3] * xA[3][c]);
      oB[c] += (pB[0] * xB[0][c] + pB[1] * xB[1][c]) + (pB[2] * xB[2][c] + pB[3] * xB[3][c]);
    }
  }
  float iA = dA > 0.f ? 1.f / dA : 0.f;
  float iB = dB > 0.f ? 1.f / dB : 0.f;
  float rA[4], rB[4];
  #pragma unroll
  for (int c = 0; c < 4; c++) {
    float vA = oA[c] * iA + bias[ca + c];
    float vB = oB[c] * iB + bias[cb + c];
    rA[c] = vA > 0.f ? vA : 0.f;         // relu after conv1
    rB[c] = vB > 0.f ? vB : 0.f;
  }
  if (H1BF) {
    unsigned short* hb = (unsigned short*)h1out;
    ushort4 ua, ub;
    ua.x = f2b(rA[0]); ua.y = f2b(rA[1]); ua.z = f2b(rA[2]); ua.w = f2b(rA[3]);
    ub.x = f2b(rB[0]); ub.y = f2b(rB[1]); ub.z = f2b(rB[2]); ub.w = f2b(rB[3]);
    *(ushort4*)&hb[(size_t)n * HC1 + ca] = ua;
    *(ushort4*)&hb[(size_t)n * HC1 + cb] = ub;
  } else {
    float* hf = (float*)h1out;
    *(float4*)&hf[(size_t)n * HC1 + ca] = *(float4*)rA;
    *(float4*)&hf[(size_t)n * HC1 + cb] = *(float4*)rB;
  }
}

// ---------------- linear2 ----------------
template<bool INBF>
__global__ __launch_bounds__(256) void linear2_kernel(
    const void* __restrict__ hin_, const float* __restrict__ Wl,
    const float* __restrict__ bl, const float* __restrict__ Wr,
    const float* __restrict__ br, float* __restrict__ xl, float* __restrict__ xr)
{
  __shared__ float xsT[HC1][16];   // 32KB
  int n0 = blockIdx.x * 16;
  int t = threadIdx.x;
  for (int r = 0; r < 8; r++) {
    int flat = (t + r * 256) * 4;
    int i = flat >> 9, k = flat & 511;
    float4 v;
    if (INBF) {
      const unsigned short* hb = (const unsigned short*)hin_;
      ushort4 u = *(const ushort4*)&hb[(size_t)(n0 + i) * HC1 + k];
      v.x = b2f(u.x); v.y = b2f(u.y); v.z = b2f(u.z); v.w = b2f(u.w);
    } else {
      const float* hf = (const float*)hin_;
      v = *(const float4*)&hf[(size_t)(n0 + i) * HC1 + k];
    }
    xsT[k + 0][i] = v.x; xsT[k + 1][i] = v.y; xsT[k + 2][i] = v.z; xsT[k + 3][i] = v.w;
  }
  __syncthreads();
  int m = t >> 7, j = t & 127;
  const float* W = m ? Wr : Wl;
  float bj = (m ? br : bl)[j];
  float* out = m ? xr : xl;
  float acc[16];
  #pragma unroll
  for (int i = 0; i < 16; i++) acc[i] = 0.f;
  for (int k = 0; k < HC1; k++) {
    float w = W[k * HID + j];
    float xv[16];
    *(float4*)&xv[0]  = *(const float4*)&xsT[k][0];
    *(float4*)&xv[4]  = *(const float4*)&xsT[k][4];
    *(float4*)&xv[8]  = *(const float4*)&xsT[k][8];
    *(float4*)&xv[12] = *(const float4*)&xsT[k][12];
    #pragma unroll
    for (int i = 0; i < 16; i++) acc[i] = fmaf(xv[i], w, acc[i]);
  }
  #pragma unroll
  for (int i = 0; i < 16; i++) out[(size_t)(n0 + i) * HID + j] = acc[i] + bj;
}

// ---------------- fused layer 2 + MLP head ----------------
// block = 512 threads = 8 waves = 8 nodes (degree-sorted). lane owns {lane, 64+lane}.
__global__ __launch_bounds__(512, 2) void fused2_kernel(
    const float* __restrict__ ea, const int* __restrict__ srcs,
    const float* __restrict__ We, const float* __restrict__ att,
    const float* __restrict__ xl, const float* __restrict__ xr,
    const float* __restrict__ bias, const int* __restrict__ offs,
    const int* __restrict__ csr, const int* __restrict__ perm,
    const float* __restrict__ Wh1, const float* __restrict__ bh1,
    const float* __restrict__ Wh2, const float* __restrict__ bh2,
    float* __restrict__ out)
{
  __shared__ float Ws[EDGE_DIM * HID];      // 16KB
  __shared__ float Wh1T[64 * 132];          // 33.8KB transposed+padded
  __shared__ float h2s[8][HID];             // 4KB
  __shared__ float eas[8][4][EDGE_DIM];     // 4KB
  int t = threadIdx.x;
  for (int i = t * 4; i < EDGE_DIM * HID; i += 2048)
    *(float4*)&Ws[i] = *(const float4*)&We[i];
  for (int i = t; i < HID * 64; i += 512) {
    int k = i >> 6, j = i & 63;
    Wh1T[j * 132 + k] = Wh1[i];
  }
  __syncthreads();
  int wave = t >> 6, lane = t & 63;
  int n = perm[blockIdx.x * 8 + wave];
  float ata = att[lane], atb = att[64 + lane];
  float xra = xr[(size_t)n * HID + lane], xrb = xr[(size_t)n * HID + 64 + lane];
  float oa = 0.f, ob = 0.f;
  float m = -3.0e38f, d = 0.f;
  int beg = offs[n], end = offs[n + 1];
  int ev = 0, sv = 0;
  if (lane < 4 && beg + lane < end) { ev = csr[beg + lane]; sv = srcs[ev]; }
  for (int i0 = beg; i0 < end; i0 += 4) {
    int nv = end - i0; if (nv > 4) nv = 4;
    int sarr[4];
    #pragma unroll
    for (int j = 0; j < 4; j++) sarr[j] = __shfl(sv, j);
    {
      int mye = __shfl(ev, lane >> 4);
      float2 eav = *(const float2*)&ea[(size_t)mye * EDGE_DIM + (lane & 15) * 2];
      *(float2*)&eas[wave][lane >> 4][(lane & 15) * 2] = eav;
    }
    float xa[4], xb[4];
    #pragma unroll
    for (int j = 0; j < 4; j++) {
      if (j < nv) {
        const float* p = &xl[(size_t)sarr[j] * HID];
        xa[j] = p[lane]; xb[j] = p[64 + lane];
      } else { xa[j] = 0.f; xb[j] = 0.f; }
    }
    if (lane < 4 && i0 + 4 + lane < end) { ev = csr[i0 + 4 + lane]; sv = srcs[ev]; }
    float aa[4], ab[4];
    #pragma unroll
    for (int j = 0; j < 4; j++) { aa[j] = 0.f; ab[j] = 0.f; }
    #pragma unroll 2
    for (int kk = 0; kk < 8; kk++) {
      float av[4][4];
      #pragma unroll
      for (int j = 0; j < 4; j++)
        *(float4*)&av[j][0] = *(const float4*)&eas[wave][j][kk * 4];
      #pragma unroll
      for (int dk = 0; dk < 4; dk++) {
        float wA = Ws[(kk * 4 + dk) * HID + lane];
        float wB = Ws[(kk * 4 + dk) * HID + 64 + lane];
        #pragma unroll
        for (int j = 0; j < 4; j++) {
          aa[j] = fmaf(av[j][dk], wA, aa[j]);
          ab[j] = fmaf(av[j][dk], wB, ab[j]);
        }
      }
    }
    float pl[4];
    #pragma unroll
    for (int j = 0; j < 4; j++) {
      float za = aa[j] + xa[j] + xra;
      float zb = ab[j] + xb[j] + xrb;
      za = za > 0.f ? za : NEG_SLOPE * za;
      zb = zb > 0.f ? zb : NEG_SLOPE * zb;
      float s = za * ata + zb * atb;
      #pragma unroll
      for (int o = 1; o < 64; o <<= 1) s += __shfl_xor(s, o);
      pl[j] = (j < nv) ? s : -3.0e38f;
    }
    float cm = fmaxf(fmaxf(pl[0], pl[1]), fmaxf(pl[2], pl[3]));
    float mn = fmaxf(m, cm);
    if (__any(mn > m + 8.f)) {
      float fs = __expf(m - mn);
      d *= fs; oa *= fs; ob *= fs;
      m = mn;
    }
    float p[4];
    #pragma unroll
    for (int j = 0; j < 4; j++) p[j] = __expf(pl[j] - m);
    d += (p[0] + p[1]) + (p[2] + p[3]);
    oa += (p[0] * xa[0] + p[1] * xa[1]) + (p[2] * xa[2] + p[3] * xa[3]);
    ob += (p[0] * xb[0] + p[1] * xb[1]) + (p[2] * xb[2] + p[3] * xb[3]);
  }
  float invd = d > 0.f ? 1.f / d : 0.f;
  float va = oa * invd + bias[lane];
  float vb = ob * invd + bias[64 + lane];   // no relu after conv2
  h2s[wave][lane] = va;
  h2s[wave][64 + lane] = vb;
  asm volatile("s_waitcnt lgkmcnt(0)" ::: "memory");
  float tacc = bh1[lane];
  #pragma unroll 8
  for (int k4 = 0; k4 < HID / 4; k4++) {
    float4 hv = *(const float4*)&h2s[wave][k4 * 4];
    float4 wv = *(const float4*)&Wh1T[lane * 132 + k4 * 4];
    tacc = fmaf(hv.x, wv.x, tacc);
    tacc = fmaf(hv.y, wv.y, tacc);
    tacc = fmaf(hv.z, wv.z, tacc);
    tacc = fmaf(hv.w, wv.w, tacc);
  }
  tacc = tacc > 0.f ? tacc : 0.f;
  float2 w2v = *(const float2*)&Wh2[lane * 2];
  float p0 = tacc * w2v.x;
  float p1 = tacc * w2v.y;
  #pragma unroll
  for (int o = 1; o < 64; o <<= 1) { p0 += __shfl_xor(p0, o); p1 += __shfl_xor(p1, o); }
  if (lane == 0) {
    float2 o2 = make_float2(p0 + bh2[0], p1 + bh2[1]);
    *(float2*)&out[(size_t)n * 2] = o2;
  }
}

extern "C" void kernel_launch(void* const* d_in, const int* in_sizes, int n_in,
                              void* d_out, int out_size, void* d_ws, size_t ws_size,
                              hipStream_t stream)
{
  (void)in_sizes; (void)n_in; (void)out_size;
  const float* x    = (const float*)d_in[0];
  const int* eidx   = (const int*)d_in[1];
  const float* ea   = (const float*)d_in[2];
  const float* Wl1  = (const float*)d_in[3];
  const float* bl1  = (const float*)d_in[4];
  const float* Wr1  = (const float*)d_in[5];
  const float* br1  = (const float*)d_in[6];
  const float* We1  = (const float*)d_in[7];
  const float* att1 = (const float*)d_in[8];
  const float* bias1= (const float*)d_in[9];
  const float* Wl2  = (const float*)d_in[10];
  const float* bl2  = (const float*)d_in[11];
  const float* Wr2  = (const float*)d_in[12];
  const float* br2  = (const float*)d_in[13];
  const float* We2  = (const float*)d_in[14];
  const float* att2 = (const float*)d_in[15];
  const float* bias2= (const float*)d_in[16];
  const float* Wh1  = (const float*)d_in[17];
  const float* bh1  = (const float*)d_in[18];
  const float* Wh2  = (const float*)d_in[19];
  const float* bh2  = (const float*)d_in[20];
  const int* srcs = eidx;
  const int* dsts = eidx + N_EDGES;
  float* out = (float*)d_out;

  const size_t szBig = (size_t)N_NODES * HC1 * sizeof(float);
  auto aln = [](size_t b) { return (b + 511) & ~(size_t)511; };
  size_t smallSz = aln((size_t)N_NODES * 4) * 3 + aln((size_t)(N_NODES + 1) * 4)
                 + aln((size_t)N_EDGES * 4) + aln(64 * 4) * 2;
  size_t needF = aln(szBig) * 3 + smallSz + 4096;
  bool useBF = ws_size < needF;

  char* p = (char*)d_ws;
  auto alloc = [&](size_t bytes) { char* q = p; p += (bytes + 511) & ~(size_t)511; return q; };
  float* xl1 = (float*)alloc(szBig);
  float* xr1 = (float*)alloc(szBig);          // reused for xl2/xr2 after fused1
  void*  h1  = (void*)alloc(useBF ? szBig / 2 : szBig);
  int* deg    = (int*)alloc((size_t)N_NODES * 4);
  int* offs   = (int*)alloc((size_t)(N_NODES + 1) * 4);
  int* cursor = (int*)alloc((size_t)N_NODES * 4);
  int* csr    = (int*)alloc((size_t)N_EDGES * 4);
  int* hist   = (int*)alloc(64 * 4);
  int* cursor2= (int*)alloc(64 * 4);
  int* perm   = (int*)alloc((size_t)N_NODES * 4);
  float* xl2 = xr1;
  float* xr2 = xr1 + (size_t)N_NODES * HID;

  hipLaunchKernelGGL(zero_deg_kernel, dim3((N_NODES + 255) / 256), dim3(256), 0, stream, deg, hist);
  hipLaunchKernelGGL(deg_count_kernel, dim3((N_EDGES + 255) / 256), dim3(256), 0, stream, dsts, deg);
  hipLaunchKernelGGL(hist_kernel, dim3((N_NODES + 255) / 256), dim3(256), 0, stream, deg, hist);
  hipLaunchKernelGGL(histscan_kernel, dim3(1), dim3(64), 0, stream, hist, cursor2);
  hipLaunchKernelGGL(permscatter_kernel, dim3((N_NODES + 255) / 256), dim3(256), 0, stream,
                     deg, cursor2, perm);
  hipLaunchKernelGGL(scan_kernel, dim3(1), dim3(1024), 0, stream, deg, offs, cursor);
  hipLaunchKernelGGL(scatter_kernel, dim3((N_EDGES + 255) / 256), dim3(256), 0, stream, dsts, cursor, csr);
  hipLaunchKernelGGL(linear1_kernel, dim3(N_NODES / 16), dim3(256), 0, stream,
                     x, Wl1, bl1, Wr1, br1, xl1, xr1);
  if (useBF)
    hipLaunchKernelGGL((fused1_kernel<true>), dim3(N_NODES / 8), dim3(512), 0, stream,
                       ea, srcs, We1, att1, xl1, xr1, bias1, offs, csr, perm, h1);
  else
    hipLaunchKernelGGL((fused1_kernel<false>), dim3(N_NODES / 8), dim3(512), 0, stream,
                       ea, srcs, We1, att1, xl1, xr1, bias1, offs, csr, perm, h1);
  if (useBF)
    hipLaunchKernelGGL((linear2_kernel<true>), dim3(N_NODES / 16), dim3(256), 0, stream,
                       h1, Wl2, bl2, Wr2, br2, xl2, xr2);
  else
    hipLaunchKernelGGL((linear2_kernel<false>), dim3(N_NODES / 16), dim3(256), 0, stream,
                       h1, Wl2, bl2, Wr2, br2, xl2, xr2);
  hipLaunchKernelGGL(fused2_kernel, dim3(N_NODES / 8), dim3(512), 0, stream,
                     ea, srcs, We2, att2, xl2, xr2, bias2, offs, csr, perm,
                     Wh1, bh1, Wh2, bh2, out);
}

// Round 6
// 720.822 us; speedup vs baseline: 1.0027x; 1.0027x over previous
//
#include <hip/hip_runtime.h>
#include <hip/hip_bf16.h>
#include <math.h>

#define N_NODES 20000
#define N_EDGES 320000
#define NODE_DIM 64
#define EDGE_DIM 32
#define HID 128
#define HEADS 4
#define HC1 512   // HEADS*HID
#define NEG_SLOPE 0.2f

__device__ __forceinline__ unsigned short f2b(float f) {
  unsigned u = __float_as_uint(f);
  unsigned r = (u + 0x7fffu + ((u >> 16) & 1u)) >> 16;
  return (unsigned short)r;
}
__device__ __forceinline__ float b2f(unsigned short b) {
  return __uint_as_float(((unsigned)b) << 16);
}

// ---------------- CSR build + degree sort ----------------
__global__ void zero_deg_kernel(int* deg, int* hist) {
  int i = blockIdx.x * blockDim.x + threadIdx.x;
  if (i < N_NODES) deg[i] = 0;
  if (i < 64) hist[i] = 0;
}

__global__ void deg_count_kernel(const int* __restrict__ dsts, int* __restrict__ deg) {
  int e = blockIdx.x * blockDim.x + threadIdx.x;
  if (e < N_EDGES) atomicAdd(&deg[dsts[e]], 1);
}

__global__ void hist_kernel(const int* __restrict__ deg, int* __restrict__ hist) {
  int n = blockIdx.x * blockDim.x + threadIdx.x;
  if (n >= N_NODES) return;
  int k = deg[n]; k = k > 63 ? 63 : k;
  atomicAdd(&hist[63 - k], 1);           // descending degree order (LPT)
}

__global__ void histscan_kernel(const int* __restrict__ hist, int* __restrict__ cursor2) {
  int lane = threadIdx.x;                 // 64 threads
  int v = hist[lane];
  int s = v;
  #pragma unroll
  for (int o = 1; o < 64; o <<= 1) { int u = __shfl_up(s, o); if (lane >= o) s += u; }
  cursor2[lane] = s - v;                  // exclusive prefix
}

__global__ void permscatter_kernel(const int* __restrict__ deg, int* __restrict__ cursor2,
                                   int* __restrict__ perm) {
  int n = blockIdx.x * blockDim.x + threadIdx.x;
  if (n >= N_NODES) return;
  int k = deg[n]; k = k > 63 ? 63 : k;
  int pos = atomicAdd(&cursor2[63 - k], 1);
  perm[pos] = n;
}

__global__ __launch_bounds__(1024) void scan_kernel(
    const int* __restrict__ deg, int* __restrict__ offs, int* __restrict__ cursor)
{
  __shared__ int part[1024];
  int t = threadIdx.x;
  const int C = 20;                 // 1024*20 = 20480 >= N_NODES
  int base = t * C;
  int loc[C]; int s = 0;
  #pragma unroll
  for (int i = 0; i < C; i++) { loc[i] = s; int idx = base + i; s += (idx < N_NODES) ? deg[idx] : 0; }
  part[t] = s;
  __syncthreads();
  for (int off = 1; off < 1024; off <<= 1) {
    int v = (t >= off) ? part[t - off] : 0;
    __syncthreads();
    part[t] += v;
    __syncthreads();
  }
  int pbase = (t > 0) ? part[t - 1] : 0;
  #pragma unroll
  for (int i = 0; i < C; i++) {
    int idx = base + i;
    if (idx < N_NODES) { int o = pbase + loc[i]; offs[idx] = o; cursor[idx] = o; }
  }
  if (t == 1023) offs[N_NODES] = part[1023];
}

__global__ void scatter_kernel(const int* __restrict__ dsts, int* __restrict__ cursor,
                               int* __restrict__ csr) {
  int e = blockIdx.x * blockDim.x + threadIdx.x;
  if (e >= N_EDGES) return;
  int pos = atomicAdd(&cursor[dsts[e]], 1);
  csr[pos] = e;
}

// ---------------- linear1 ----------------
__global__ __launch_bounds__(256) void linear1_kernel(
    const float* __restrict__ x, const float* __restrict__ Wl,
    const float* __restrict__ bl, const float* __restrict__ Wr,
    const float* __restrict__ br, float* __restrict__ xl, float* __restrict__ xr)
{
  __shared__ float xsT[NODE_DIM][16];
  int n0 = blockIdx.x * 16;
  int t = threadIdx.x;
  {
    int flat = t * 4;
    int i = flat >> 6, k = flat & 63;
    float4 v = *(const float4*)&x[(size_t)(n0 + i) * NODE_DIM + k];
    xsT[k + 0][i] = v.x; xsT[k + 1][i] = v.y; xsT[k + 2][i] = v.z; xsT[k + 3][i] = v.w;
  }
  __syncthreads();
  for (int m = 0; m < 2; m++) {
    const float* W  = m ? Wr : Wl;
    const float* bb = m ? br : bl;
    float* out = m ? xr : xl;
    for (int jh = 0; jh < 2; jh++) {
      int j = t + jh * 256;
      float acc[16];
      #pragma unroll
      for (int i = 0; i < 16; i++) acc[i] = 0.f;
      for (int k = 0; k < NODE_DIM; k++) {
        float w = W[k * HC1 + j];
        float xv[16];
        *(float4*)&xv[0]  = *(const float4*)&xsT[k][0];
        *(float4*)&xv[4]  = *(const float4*)&xsT[k][4];
        *(float4*)&xv[8]  = *(const float4*)&xsT[k][8];
        *(float4*)&xv[12] = *(const float4*)&xsT[k][12];
        #pragma unroll
        for (int i = 0; i < 16; i++) acc[i] = fmaf(xv[i], w, acc[i]);
      }
      float bj = bb[j];
      #pragma unroll
      for (int i = 0; i < 16; i++) out[(size_t)(n0 + i) * HC1 + j] = acc[i] + bj;
    }
  }
}

// ---------------- fused layer 1 ----------------
// block = 1024 threads = 16 waves; 2 waves per node (half = wave&1), 8 nodes/block.
// lane owns 4 channels: C = half*256 + lane*4. Head = C>>7 -> 32-lane butterfly groups.
// launch_bounds(1024,2): 2 blocks/CU -> 32 waves/CU -> 64-VGPR budget.
template<bool H1BF>
__global__ __launch_bounds__(1024, 2) void fused1_kernel(
    const float* __restrict__ ea, const int* __restrict__ srcs,
    const float* __restrict__ We, const float* __restrict__ att,
    const float* __restrict__ xl, const float* __restrict__ xr,
    const float* __restrict__ bias, const int* __restrict__ offs,
    const int* __restrict__ csr, const int* __restrict__ perm,
    void* __restrict__ h1out)
{
  __shared__ float Ws[EDGE_DIM * HC1];     // 64KB
  __shared__ float eas[16][4][EDGE_DIM];   // 8KB, per-wave chunk ea tile
  int t = threadIdx.x;
  for (int i = t * 4; i < EDGE_DIM * HC1; i += 4096)
    *(float4*)&Ws[i] = *(const float4*)&We[i];
  __syncthreads();
  int wave = t >> 6, lane = t & 63;
  int n = perm[blockIdx.x * 8 + (wave >> 1)];   // 2500*8 = 20000 exact
  int half = wave & 1;
  int C = half * 256 + lane * 4;
  float at4[4], xr4[4];
  *(float4*)at4 = *(const float4*)&att[C];
  *(float4*)xr4 = *(const float4*)&xr[(size_t)n * HC1 + C];
  float o4[4] = {0.f,0.f,0.f,0.f};
  float mx = -3.0e38f, dn = 0.f;
  int beg = offs[n], end = offs[n + 1];
  int ev = 0, sv = 0;
  if (lane < 4 && beg + lane < end) { ev = csr[beg + lane]; sv = srcs[ev]; }
  for (int i0 = beg; i0 < end; i0 += 4) {
    int nv = end - i0; if (nv > 4) nv = 4;
    int sarr[4];
    #pragma unroll
    for (int j = 0; j < 4; j++) sarr[j] = __shfl(sv, j);
    // stage this chunk's ea rows into per-wave LDS (coalesced float2/lane)
    {
      int mye = __shfl(ev, lane >> 4);
      float2 eav = *(const float2*)&ea[(size_t)mye * EDGE_DIM + (lane & 15) * 2];
      *(float2*)&eas[wave][lane >> 4][(lane & 15) * 2] = eav;
    }
    // acc init = xl + xr (gather xl; frees the separate xl hold)
    float a4[4][4];
    #pragma unroll
    for (int j = 0; j < 4; j++) {
      if (j < nv) {
        float4 xv = *(const float4*)&xl[(size_t)sarr[j] * HC1 + C];
        a4[j][0] = xv.x + xr4[0]; a4[j][1] = xv.y + xr4[1];
        a4[j][2] = xv.z + xr4[2]; a4[j][3] = xv.w + xr4[3];
      } else {
        a4[j][0] = 0.f; a4[j][1] = 0.f; a4[j][2] = 0.f; a4[j][3] = 0.f;
      }
    }
    // prefetch next chunk's indices
    if (lane < 4 && i0 + 4 + lane < end) { ev = csr[i0 + 4 + lane]; sv = srcs[ev]; }
    // ee-GEMM: z = xl + xr + ea@We accumulated in place
    #pragma unroll 1
    for (int kk = 0; kk < 8; kk++) {
      float w0[4], w1[4], w2[4], w3[4];
      *(float4*)w0 = *(const float4*)&Ws[(kk * 4 + 0) * HC1 + C];
      *(float4*)w1 = *(const float4*)&Ws[(kk * 4 + 1) * HC1 + C];
      *(float4*)w2 = *(const float4*)&Ws[(kk * 4 + 2) * HC1 + C];
      *(float4*)w3 = *(const float4*)&Ws[(kk * 4 + 3) * HC1 + C];
      #pragma unroll
      for (int j = 0; j < 4; j++) {
        float av[4];
        *(float4*)av = *(const float4*)&eas[wave][j][kk * 4];
        #pragma unroll
        for (int c = 0; c < 4; c++) {
          a4[j][c] = fmaf(av[0], w0[c], a4[j][c]);
          a4[j][c] = fmaf(av[1], w1[c], a4[j][c]);
          a4[j][c] = fmaf(av[2], w2[c], a4[j][c]);
          a4[j][c] = fmaf(av[3], w3[c], a4[j][c]);
        }
      }
    }
    // logits: leakyrelu + att dot, 32-lane (one head) butterflies
    float pl[4];
    #pragma unroll
    for (int j = 0; j < 4; j++) {
      float s = 0.f;
      #pragma unroll
      for (int c = 0; c < 4; c++) {
        float z = a4[j][c];
        float zm = z > 0.f ? z : NEG_SLOPE * z;
        s = fmaf(zm, at4[c], s);
      }
      #pragma unroll
      for (int o = 1; o <= 16; o <<= 1) s += __shfl_xor(s, o);
      pl[j] = (j < nv) ? s : -3.0e38f;
    }
    // issue xl re-gather now (latency covered by softmax math below)
    float xv0[4], xv1[4], xv2[4], xv3[4];
    if (0 < nv) *(float4*)xv0 = *(const float4*)&xl[(size_t)sarr[0] * HC1 + C];
    if (1 < nv) *(float4*)xv1 = *(const float4*)&xl[(size_t)sarr[1] * HC1 + C];
    if (2 < nv) *(float4*)xv2 = *(const float4*)&xl[(size_t)sarr[2] * HC1 + C];
    if (3 < nv) *(float4*)xv3 = *(const float4*)&xl[(size_t)sarr[3] * HC1 + C];
    // defer-max online softmax
    float cm = fmaxf(fmaxf(pl[0], pl[1]), fmaxf(pl[2], pl[3]));
    float mn = fmaxf(mx, cm);
    if (__any(mn > mx + 8.f)) {
      float fs = __expf(mx - mn);
      dn *= fs;
      #pragma unroll
      for (int c = 0; c < 4; c++) o4[c] *= fs;
      mx = mn;
    }
    float p[4];
    #pragma unroll
    for (int j = 0; j < 4; j++) p[j] = __expf(pl[j] - mx);
    dn += (p[0] + p[1]) + (p[2] + p[3]);
    if (0 < nv) { o4[0] = fmaf(p[0], xv0[0], o4[0]); o4[1] = fmaf(p[0], xv0[1], o4[1]);
                  o4[2] = fmaf(p[0], xv0[2], o4[2]); o4[3] = fmaf(p[0], xv0[3], o4[3]); }
    if (1 < nv) { o4[0] = fmaf(p[1], xv1[0], o4[0]); o4[1] = fmaf(p[1], xv1[1], o4[1]);
                  o4[2] = fmaf(p[1], xv1[2], o4[2]); o4[3] = fmaf(p[1], xv1[3], o4[3]); }
    if (2 < nv) { o4[0] = fmaf(p[2], xv2[0], o4[0]); o4[1] = fmaf(p[2], xv2[1], o4[1]);
                  o4[2] = fmaf(p[2], xv2[2], o4[2]); o4[3] = fmaf(p[2], xv2[3], o4[3]); }
    if (3 < nv) { o4[0] = fmaf(p[3], xv3[0], o4[0]); o4[1] = fmaf(p[3], xv3[1], o4[1]);
                  o4[2] = fmaf(p[3], xv3[2], o4[2]); o4[3] = fmaf(p[3], xv3[3], o4[3]); }
  }
  float iv = dn > 0.f ? 1.f / dn : 0.f;
  float r[4];
  #pragma unroll
  for (int c = 0; c < 4; c++) {
    float v = o4[c] * iv + bias[C + c];
    r[c] = v > 0.f ? v : 0.f;            // relu after conv1
  }
  if (H1BF) {
    unsigned short* hb = (unsigned short*)h1out;
    ushort4 u;
    u.x = f2b(r[0]); u.y = f2b(r[1]); u.z = f2b(r[2]); u.w = f2b(r[3]);
    *(ushort4*)&hb[(size_t)n * HC1 + C] = u;
  } else {
    float* hf = (float*)h1out;
    *(float4*)&hf[(size_t)n * HC1 + C] = *(float4*)r;
  }
}

// ---------------- linear2 ----------------
template<bool INBF>
__global__ __launch_bounds__(256) void linear2_kernel(
    const void* __restrict__ hin_, const float* __restrict__ Wl,
    const float* __restrict__ bl, const float* __restrict__ Wr,
    const float* __restrict__ br, float* __restrict__ xl, float* __restrict__ xr)
{
  __shared__ float xsT[HC1][16];   // 32KB
  int n0 = blockIdx.x * 16;
  int t = threadIdx.x;
  for (int r = 0; r < 8; r++) {
    int flat = (t + r * 256) * 4;
    int i = flat >> 9, k = flat & 511;
    float4 v;
    if (INBF) {
      const unsigned short* hb = (const unsigned short*)hin_;
      ushort4 u = *(const ushort4*)&hb[(size_t)(n0 + i) * HC1 + k];
      v.x = b2f(u.x); v.y = b2f(u.y); v.z = b2f(u.z); v.w = b2f(u.w);
    } else {
      const float* hf = (const float*)hin_;
      v = *(const float4*)&hf[(size_t)(n0 + i) * HC1 + k];
    }
    xsT[k + 0][i] = v.x; xsT[k + 1][i] = v.y; xsT[k + 2][i] = v.z; xsT[k + 3][i] = v.w;
  }
  __syncthreads();
  int m = t >> 7, j = t & 127;
  const float* W = m ? Wr : Wl;
  float bj = (m ? br : bl)[j];
  float* out = m ? xr : xl;
  float acc[16];
  #pragma unroll
  for (int i = 0; i < 16; i++) acc[i] = 0.f;
  for (int k = 0; k < HC1; k++) {
    float w = W[k * HID + j];
    float xv[16];
    *(float4*)&xv[0]  = *(const float4*)&xsT[k][0];
    *(float4*)&xv[4]  = *(const float4*)&xsT[k][4];
    *(float4*)&xv[8]  = *(const float4*)&xsT[k][8];
    *(float4*)&xv[12] = *(const float4*)&xsT[k][12];
    #pragma unroll
    for (int i = 0; i < 16; i++) acc[i] = fmaf(xv[i], w, acc[i]);
  }
  #pragma unroll
  for (int i = 0; i < 16; i++) out[(size_t)(n0 + i) * HID + j] = acc[i] + bj;
}

// ---------------- fused layer 2 + MLP head (round-4 version) ----------------
// block = 512 threads = 8 waves = 8 nodes. lane owns channels {lane, 64+lane}.
__global__ __launch_bounds__(512, 2) void fused2_kernel(
    const float* __restrict__ ea, const int* __restrict__ srcs,
    const float* __restrict__ We, const float* __restrict__ att,
    const float* __restrict__ xl, const float* __restrict__ xr,
    const float* __restrict__ bias, const int* __restrict__ offs,
    const int* __restrict__ csr, const float* __restrict__ Wh1,
    const float* __restrict__ bh1, const float* __restrict__ Wh2,
    const float* __restrict__ bh2, float* __restrict__ out)
{
  __shared__ float Ws[EDGE_DIM * HID];      // 16KB
  __shared__ float Wh1T[64 * 132];          // 33.8KB transposed+padded
  __shared__ float h2s[8][HID];             // 4KB
  int t = threadIdx.x;
  for (int i = t * 4; i < EDGE_DIM * HID; i += 2048)
    *(float4*)&Ws[i] = *(const float4*)&We[i];
  for (int i = t; i < HID * 64; i += 512) {
    int k = i >> 6, j = i & 63;
    Wh1T[j * 132 + k] = Wh1[i];
  }
  __syncthreads();
  int wave = t >> 6, lane = t & 63;
  int n = blockIdx.x * 8 + wave;
  float ata = att[lane], atb = att[64 + lane];
  float xra = xr[(size_t)n * HID + lane], xrb = xr[(size_t)n * HID + 64 + lane];
  float oa = 0.f, ob = 0.f;
  float m = -3.0e38f, d = 0.f;
  int beg = offs[n], end = offs[n + 1];
  int ev = 0, sv = 0;
  if (lane < 4 && beg + lane < end) { ev = csr[beg + lane]; sv = srcs[ev]; }
  for (int i0 = beg; i0 < end; i0 += 4) {
    int nv = end - i0; if (nv > 4) nv = 4;
    int earr[4], sarr[4];
    #pragma unroll
    for (int j = 0; j < 4; j++) { earr[j] = __shfl(ev, j); sarr[j] = __shfl(sv, j); }
    float xa[4], xb[4];
    #pragma unroll
    for (int j = 0; j < 4; j++) {
      if (j < nv) {
        const float* p = &xl[(size_t)sarr[j] * HID];
        xa[j] = p[lane]; xb[j] = p[64 + lane];
      } else { xa[j] = 0.f; xb[j] = 0.f; }
    }
    if (lane < 4 && i0 + 4 + lane < end) { ev = csr[i0 + 4 + lane]; sv = srcs[ev]; }
    float aa[4], ab[4];
    #pragma unroll
    for (int j = 0; j < 4; j++) { aa[j] = 0.f; ab[j] = 0.f; }
    #pragma unroll 1
    for (int kk = 0; kk < 8; kk++) {
      float av[4][4];
      #pragma unroll
      for (int j = 0; j < 4; j++)
        *(float4*)&av[j][0] = *(const float4*)&ea[(size_t)earr[j] * EDGE_DIM + kk * 4];
      #pragma unroll
      for (int dk = 0; dk < 4; dk++) {
        float wA = Ws[(kk * 4 + dk) * HID + lane];
        float wB = Ws[(kk * 4 + dk) * HID + 64 + lane];
        #pragma unroll
        for (int j = 0; j < 4; j++) {
          aa[j] = fmaf(av[j][dk], wA, aa[j]);
          ab[j] = fmaf(av[j][dk], wB, ab[j]);
        }
      }
    }
    float pl[4];
    #pragma unroll
    for (int j = 0; j < 4; j++) {
      float za = aa[j] + xa[j] + xra;
      float zb = ab[j] + xb[j] + xrb;
      za = za > 0.f ? za : NEG_SLOPE * za;
      zb = zb > 0.f ? zb : NEG_SLOPE * zb;
      float s = za * ata + zb * atb;
      #pragma unroll
      for (int o = 1; o < 64; o <<= 1) s += __shfl_xor(s, o);
      pl[j] = (j < nv) ? s : -3.0e38f;
    }
    float cm = fmaxf(fmaxf(pl[0], pl[1]), fmaxf(pl[2], pl[3]));
    float mn = fmaxf(m, cm);
    if (__any(mn > m + 8.f)) {
      float fs = __expf(m - mn);
      d *= fs; oa *= fs; ob *= fs;
      m = mn;
    }
    float p[4];
    #pragma unroll
    for (int j = 0; j < 4; j++) p[j] = __expf(pl[j] - m);
    d += (p[0] + p[1]) + (p[2] + p[3]);
    oa += (p[0] * xa[0] + p[1] * xa[1]) + (p[2] * xa[2] + p[3] * xa[3]);
    ob += (p[0] * xb[0] + p[1] * xb[1]) + (p[2] * xb[2] + p[3] * xb[3]);
  }
  float invd = d > 0.f ? 1.f / d : 0.f;
  float va = oa * invd + bias[lane];
  float vb = ob * invd + bias[64 + lane];   // no relu after conv2
  h2s[wave][lane] = va;
  h2s[wave][64 + lane] = vb;
  asm volatile("s_waitcnt lgkmcnt(0)" ::: "memory");
  float tacc = bh1[lane];
  #pragma unroll 8
  for (int k4 = 0; k4 < HID / 4; k4++) {
    float4 hv = *(const float4*)&h2s[wave][k4 * 4];
    float4 wv = *(const float4*)&Wh1T[lane * 132 + k4 * 4];
    tacc = fmaf(hv.x, wv.x, tacc);
    tacc = fmaf(hv.y, wv.y, tacc);
    tacc = fmaf(hv.z, wv.z, tacc);
    tacc = fmaf(hv.w, wv.w, tacc);
  }
  tacc = tacc > 0.f ? tacc : 0.f;
  float2 w2v = *(const float2*)&Wh2[lane * 2];
  float p0 = tacc * w2v.x;
  float p1 = tacc * w2v.y;
  #pragma unroll
  for (int o = 1; o < 64; o <<= 1) { p0 += __shfl_xor(p0, o); p1 += __shfl_xor(p1, o); }
  if (lane == 0) {
    float2 o2 = make_float2(p0 + bh2[0], p1 + bh2[1]);
    *(float2*)&out[(size_t)n * 2] = o2;
  }
}

extern "C" void kernel_launch(void* const* d_in, const int* in_sizes, int n_in,
                              void* d_out, int out_size, void* d_ws, size_t ws_size,
                              hipStream_t stream)
{
  (void)in_sizes; (void)n_in; (void)out_size;
  const float* x    = (const float*)d_in[0];
  const int* eidx   = (const int*)d_in[1];
  const float* ea   = (const float*)d_in[2];
  const float* Wl1  = (const float*)d_in[3];
  const float* bl1  = (const float*)d_in[4];
  const float* Wr1  = (const float*)d_in[5];
  const float* br1  = (const float*)d_in[6];
  const float* We1  = (const float*)d_in[7];
  const float* att1 = (const float*)d_in[8];
  const float* bias1= (const float*)d_in[9];
  const float* Wl2  = (const float*)d_in[10];
  const float* bl2  = (const float*)d_in[11];
  const float* Wr2  = (const float*)d_in[12];
  const float* br2  = (const float*)d_in[13];
  const float* We2  = (const float*)d_in[14];
  const float* att2 = (const float*)d_in[15];
  const float* bias2= (const float*)d_in[16];
  const float* Wh1  = (const float*)d_in[17];
  const float* bh1  = (const float*)d_in[18];
  const float* Wh2  = (const float*)d_in[19];
  const float* bh2  = (const float*)d_in[20];
  const int* srcs = eidx;
  const int* dsts = eidx + N_EDGES;
  float* out = (float*)d_out;

  const size_t szBig = (size_t)N_NODES * HC1 * sizeof(float);
  auto aln = [](size_t b) { return (b + 511) & ~(size_t)511; };
  size_t smallSz = aln((size_t)N_NODES * 4) * 3 + aln((size_t)(N_NODES + 1) * 4)
                 + aln((size_t)N_EDGES * 4) + aln(64 * 4) * 2;
  size_t needF = aln(szBig) * 3 + smallSz + 4096;
  bool useBF = ws_size < needF;

  char* p = (char*)d_ws;
  auto alloc = [&](size_t bytes) { char* q = p; p += (bytes + 511) & ~(size_t)511; return q; };
  float* xl1 = (float*)alloc(szBig);
  float* xr1 = (float*)alloc(szBig);          // reused for xl2/xr2 after fused1
  void*  h1  = (void*)alloc(useBF ? szBig / 2 : szBig);
  int* deg    = (int*)alloc((size_t)N_NODES * 4);
  int* offs   = (int*)alloc((size_t)(N_NODES + 1) * 4);
  int* cursor = (int*)alloc((size_t)N_NODES * 4);
  int* csr    = (int*)alloc((size_t)N_EDGES * 4);
  int* hist   = (int*)alloc(64 * 4);
  int* cursor2= (int*)alloc(64 * 4);
  int* perm   = (int*)alloc((size_t)N_NODES * 4);
  float* xl2 = xr1;
  float* xr2 = xr1 + (size_t)N_NODES * HID;

  hipLaunchKernelGGL(zero_deg_kernel, dim3((N_NODES + 255) / 256), dim3(256), 0, stream, deg, hist);
  hipLaunchKernelGGL(deg_count_kernel, dim3((N_EDGES + 255) / 256), dim3(256), 0, stream, dsts, deg);
  hipLaunchKernelGGL(hist_kernel, dim3((N_NODES + 255) / 256), dim3(256), 0, stream, deg, hist);
  hipLaunchKernelGGL(histscan_kernel, dim3(1), dim3(64), 0, stream, hist, cursor2);
  hipLaunchKernelGGL(permscatter_kernel, dim3((N_NODES + 255) / 256), dim3(256), 0, stream,
                     deg, cursor2, perm);
  hipLaunchKernelGGL(scan_kernel, dim3(1), dim3(1024), 0, stream, deg, offs, cursor);
  hipLaunchKernelGGL(scatter_kernel, dim3((N_EDGES + 255) / 256), dim3(256), 0, stream, dsts, cursor, csr);
  hipLaunchKernelGGL(linear1_kernel, dim3(N_NODES / 16), dim3(256), 0, stream,
                     x, Wl1, bl1, Wr1, br1, xl1, xr1);
  if (useBF)
    hipLaunchKernelGGL((fused1_kernel<true>), dim3(N_NODES / 8), dim3(1024), 0, stream,
                       ea, srcs, We1, att1, xl1, xr1, bias1, offs, csr, perm, h1);
  else
    hipLaunchKernelGGL((fused1_kernel<false>), dim3(N_NODES / 8), dim3(1024), 0, stream,
                       ea, srcs, We1, att1, xl1, xr1, bias1, offs, csr, perm, h1);
  if (useBF)
    hipLaunchKernelGGL((linear2_kernel<true>), dim3(N_NODES / 16), dim3(256), 0, stream,
                       h1, Wl2, bl2, Wr2, br2, xl2, xr2);
  else
    hipLaunchKernelGGL((linear2_kernel<false>), dim3(N_NODES / 16), dim3(256), 0, stream,
                       h1, Wl2, bl2, Wr2, br2, xl2, xr2);
  hipLaunchKernelGGL(fused2_kernel, dim3(N_NODES / 8), dim3(512), 0, stream,
                     ea, srcs, We2, att2, xl2, xr2, bias2, offs, csr,
                     Wh1, bh1, Wh2, bh2, out);
}

// Round 7
// 674.914 us; speedup vs baseline: 1.0709x; 1.0680x over previous
//
#include <hip/hip_runtime.h>
#include <hip/hip_bf16.h>
#include <math.h>

#define N_NODES 20000
#define N_EDGES 320000
#define NODE_DIM 64
#define EDGE_DIM 32
#define HID 128
#define HEADS 4
#define HC1 512   // HEADS*HID
#define NEG_SLOPE 0.2f

__device__ __forceinline__ unsigned short f2b(float f) {
  unsigned u = __float_as_uint(f);
  unsigned r = (u + 0x7fffu + ((u >> 16) & 1u)) >> 16;
  return (unsigned short)r;
}
__device__ __forceinline__ float b2f(unsigned short b) {
  return __uint_as_float(((unsigned)b) << 16);
}

// ---------------- CSR build + degree sort ----------------
__global__ void zero_deg_kernel(int* deg, int* hist) {
  int i = blockIdx.x * blockDim.x + threadIdx.x;
  if (i < N_NODES) deg[i] = 0;
  if (i < 64) hist[i] = 0;
}

__global__ void deg_count_kernel(const int* __restrict__ dsts, int* __restrict__ deg) {
  int e = blockIdx.x * blockDim.x + threadIdx.x;
  if (e < N_EDGES) atomicAdd(&deg[dsts[e]], 1);
}

__global__ void hist_kernel(const int* __restrict__ deg, int* __restrict__ hist) {
  int n = blockIdx.x * blockDim.x + threadIdx.x;
  if (n >= N_NODES) return;
  int k = deg[n]; k = k > 63 ? 63 : k;
  atomicAdd(&hist[63 - k], 1);           // descending degree order (LPT)
}

__global__ void histscan_kernel(const int* __restrict__ hist, int* __restrict__ cursor2) {
  int lane = threadIdx.x;                 // 64 threads
  int v = hist[lane];
  int s = v;
  #pragma unroll
  for (int o = 1; o < 64; o <<= 1) { int u = __shfl_up(s, o); if (lane >= o) s += u; }
  cursor2[lane] = s - v;                  // exclusive prefix
}

__global__ void permscatter_kernel(const int* __restrict__ deg, int* __restrict__ cursor2,
                                   int* __restrict__ perm) {
  int n = blockIdx.x * blockDim.x + threadIdx.x;
  if (n >= N_NODES) return;
  int k = deg[n]; k = k > 63 ? 63 : k;
  int pos = atomicAdd(&cursor2[63 - k], 1);
  perm[pos] = n;
}

__global__ __launch_bounds__(1024) void scan_kernel(
    const int* __restrict__ deg, int* __restrict__ offs, int* __restrict__ cursor)
{
  __shared__ int part[1024];
  int t = threadIdx.x;
  const int C = 20;                 // 1024*20 = 20480 >= N_NODES
  int base = t * C;
  int loc[C]; int s = 0;
  #pragma unroll
  for (int i = 0; i < C; i++) { loc[i] = s; int idx = base + i; s += (idx < N_NODES) ? deg[idx] : 0; }
  part[t] = s;
  __syncthreads();
  for (int off = 1; off < 1024; off <<= 1) {
    int v = (t >= off) ? part[t - off] : 0;
    __syncthreads();
    part[t] += v;
    __syncthreads();
  }
  int pbase = (t > 0) ? part[t - 1] : 0;
  #pragma unroll
  for (int i = 0; i < C; i++) {
    int idx = base + i;
    if (idx < N_NODES) { int o = pbase + loc[i]; offs[idx] = o; cursor[idx] = o; }
  }
  if (t == 1023) offs[N_NODES] = part[1023];
}

__global__ void scatter_kernel(const int* __restrict__ dsts, int* __restrict__ cursor,
                               int* __restrict__ csr) {
  int e = blockIdx.x * blockDim.x + threadIdx.x;
  if (e >= N_EDGES) return;
  int pos = atomicAdd(&cursor[dsts[e]], 1);
  csr[pos] = e;
}

// ---------------- linear1 ----------------
__global__ __launch_bounds__(256) void linear1_kernel(
    const float* __restrict__ x, const float* __restrict__ Wl,
    const float* __restrict__ bl, const float* __restrict__ Wr,
    const float* __restrict__ br, float* __restrict__ xl, float* __restrict__ xr)
{
  __shared__ float xsT[NODE_DIM][16];
  int n0 = blockIdx.x * 16;
  int t = threadIdx.x;
  {
    int flat = t * 4;
    int i = flat >> 6, k = flat & 63;
    float4 v = *(const float4*)&x[(size_t)(n0 + i) * NODE_DIM + k];
    xsT[k + 0][i] = v.x; xsT[k + 1][i] = v.y; xsT[k + 2][i] = v.z; xsT[k + 3][i] = v.w;
  }
  __syncthreads();
  for (int m = 0; m < 2; m++) {
    const float* W  = m ? Wr : Wl;
    const float* bb = m ? br : bl;
    float* out = m ? xr : xl;
    for (int jh = 0; jh < 2; jh++) {
      int j = t + jh * 256;
      float acc[16];
      #pragma unroll
      for (int i = 0; i < 16; i++) acc[i] = 0.f;
      for (int k = 0; k < NODE_DIM; k++) {
        float w = W[k * HC1 + j];
        float xv[16];
        *(float4*)&xv[0]  = *(const float4*)&xsT[k][0];
        *(float4*)&xv[4]  = *(const float4*)&xsT[k][4];
        *(float4*)&xv[8]  = *(const float4*)&xsT[k][8];
        *(float4*)&xv[12] = *(const float4*)&xsT[k][12];
        #pragma unroll
        for (int i = 0; i < 16; i++) acc[i] = fmaf(xv[i], w, acc[i]);
      }
      float bj = bb[j];
      #pragma unroll
      for (int i = 0; i < 16; i++) out[(size_t)(n0 + i) * HC1 + j] = acc[i] + bj;
    }
  }
}

// ---------------- fused layer 1 (unchanged from round 6) ----------------
template<bool H1BF>
__global__ __launch_bounds__(1024, 2) void fused1_kernel(
    const float* __restrict__ ea, const int* __restrict__ srcs,
    const float* __restrict__ We, const float* __restrict__ att,
    const float* __restrict__ xl, const float* __restrict__ xr,
    const float* __restrict__ bias, const int* __restrict__ offs,
    const int* __restrict__ csr, const int* __restrict__ perm,
    void* __restrict__ h1out)
{
  __shared__ float Ws[EDGE_DIM * HC1];     // 64KB
  __shared__ float eas[16][4][EDGE_DIM];   // 8KB, per-wave chunk ea tile
  int t = threadIdx.x;
  for (int i = t * 4; i < EDGE_DIM * HC1; i += 4096)
    *(float4*)&Ws[i] = *(const float4*)&We[i];
  __syncthreads();
  int wave = t >> 6, lane = t & 63;
  int n = perm[blockIdx.x * 8 + (wave >> 1)];   // 2500*8 = 20000 exact
  int half = wave & 1;
  int C = half * 256 + lane * 4;
  float at4[4], xr4[4];
  *(float4*)at4 = *(const float4*)&att[C];
  *(float4*)xr4 = *(const float4*)&xr[(size_t)n * HC1 + C];
  float o4[4] = {0.f,0.f,0.f,0.f};
  float mx = -3.0e38f, dn = 0.f;
  int beg = offs[n], end = offs[n + 1];
  int ev = 0, sv = 0;
  if (lane < 4 && beg + lane < end) { ev = csr[beg + lane]; sv = srcs[ev]; }
  for (int i0 = beg; i0 < end; i0 += 4) {
    int nv = end - i0; if (nv > 4) nv = 4;
    int sarr[4];
    #pragma unroll
    for (int j = 0; j < 4; j++) sarr[j] = __shfl(sv, j);
    // stage this chunk's ea rows into per-wave LDS (coalesced float2/lane)
    {
      int mye = __shfl(ev, lane >> 4);
      float2 eav = *(const float2*)&ea[(size_t)mye * EDGE_DIM + (lane & 15) * 2];
      *(float2*)&eas[wave][lane >> 4][(lane & 15) * 2] = eav;
    }
    // acc init = xl + xr (gather xl; frees the separate xl hold)
    float a4[4][4];
    #pragma unroll
    for (int j = 0; j < 4; j++) {
      if (j < nv) {
        float4 xv = *(const float4*)&xl[(size_t)sarr[j] * HC1 + C];
        a4[j][0] = xv.x + xr4[0]; a4[j][1] = xv.y + xr4[1];
        a4[j][2] = xv.z + xr4[2]; a4[j][3] = xv.w + xr4[3];
      } else {
        a4[j][0] = 0.f; a4[j][1] = 0.f; a4[j][2] = 0.f; a4[j][3] = 0.f;
      }
    }
    // prefetch next chunk's indices
    if (lane < 4 && i0 + 4 + lane < end) { ev = csr[i0 + 4 + lane]; sv = srcs[ev]; }
    // ee-GEMM: z = xl + xr + ea@We accumulated in place
    #pragma unroll 1
    for (int kk = 0; kk < 8; kk++) {
      float w0[4], w1[4], w2[4], w3[4];
      *(float4*)w0 = *(const float4*)&Ws[(kk * 4 + 0) * HC1 + C];
      *(float4*)w1 = *(const float4*)&Ws[(kk * 4 + 1) * HC1 + C];
      *(float4*)w2 = *(const float4*)&Ws[(kk * 4 + 2) * HC1 + C];
      *(float4*)w3 = *(const float4*)&Ws[(kk * 4 + 3) * HC1 + C];
      #pragma unroll
      for (int j = 0; j < 4; j++) {
        float av[4];
        *(float4*)av = *(const float4*)&eas[wave][j][kk * 4];
        #pragma unroll
        for (int c = 0; c < 4; c++) {
          a4[j][c] = fmaf(av[0], w0[c], a4[j][c]);
          a4[j][c] = fmaf(av[1], w1[c], a4[j][c]);
          a4[j][c] = fmaf(av[2], w2[c], a4[j][c]);
          a4[j][c] = fmaf(av[3], w3[c], a4[j][c]);
        }
      }
    }
    // logits: leakyrelu + att dot, 32-lane (one head) butterflies
    float pl[4];
    #pragma unroll
    for (int j = 0; j < 4; j++) {
      float s = 0.f;
      #pragma unroll
      for (int c = 0; c < 4; c++) {
        float z = a4[j][c];
        float zm = z > 0.f ? z : NEG_SLOPE * z;
        s = fmaf(zm, at4[c], s);
      }
      #pragma unroll
      for (int o = 1; o <= 16; o <<= 1) s += __shfl_xor(s, o);
      pl[j] = (j < nv) ? s : -3.0e38f;
    }
    // issue xl re-gather now (latency covered by softmax math below)
    float xv0[4], xv1[4], xv2[4], xv3[4];
    if (0 < nv) *(float4*)xv0 = *(const float4*)&xl[(size_t)sarr[0] * HC1 + C];
    if (1 < nv) *(float4*)xv1 = *(const float4*)&xl[(size_t)sarr[1] * HC1 + C];
    if (2 < nv) *(float4*)xv2 = *(const float4*)&xl[(size_t)sarr[2] * HC1 + C];
    if (3 < nv) *(float4*)xv3 = *(const float4*)&xl[(size_t)sarr[3] * HC1 + C];
    // defer-max online softmax
    float cm = fmaxf(fmaxf(pl[0], pl[1]), fmaxf(pl[2], pl[3]));
    float mn = fmaxf(mx, cm);
    if (__any(mn > mx + 8.f)) {
      float fs = __expf(mx - mn);
      dn *= fs;
      #pragma unroll
      for (int c = 0; c < 4; c++) o4[c] *= fs;
      mx = mn;
    }
    float p[4];
    #pragma unroll
    for (int j = 0; j < 4; j++) p[j] = __expf(pl[j] - mx);
    dn += (p[0] + p[1]) + (p[2] + p[3]);
    if (0 < nv) { o4[0] = fmaf(p[0], xv0[0], o4[0]); o4[1] = fmaf(p[0], xv0[1], o4[1]);
                  o4[2] = fmaf(p[0], xv0[2], o4[2]); o4[3] = fmaf(p[0], xv0[3], o4[3]); }
    if (1 < nv) { o4[0] = fmaf(p[1], xv1[0], o4[0]); o4[1] = fmaf(p[1], xv1[1], o4[1]);
                  o4[2] = fmaf(p[1], xv1[2], o4[2]); o4[3] = fmaf(p[1], xv1[3], o4[3]); }
    if (2 < nv) { o4[0] = fmaf(p[2], xv2[0], o4[0]); o4[1] = fmaf(p[2], xv2[1], o4[1]);
                  o4[2] = fmaf(p[2], xv2[2], o4[2]); o4[3] = fmaf(p[2], xv2[3], o4[3]); }
    if (3 < nv) { o4[0] = fmaf(p[3], xv3[0], o4[0]); o4[1] = fmaf(p[3], xv3[1], o4[1]);
                  o4[2] = fmaf(p[3], xv3[2], o4[2]); o4[3] = fmaf(p[3], xv3[3], o4[3]); }
  }
  float iv = dn > 0.f ? 1.f / dn : 0.f;
  float r[4];
  #pragma unroll
  for (int c = 0; c < 4; c++) {
    float v = o4[c] * iv + bias[C + c];
    r[c] = v > 0.f ? v : 0.f;            // relu after conv1
  }
  if (H1BF) {
    unsigned short* hb = (unsigned short*)h1out;
    ushort4 u;
    u.x = f2b(r[0]); u.y = f2b(r[1]); u.z = f2b(r[2]); u.w = f2b(r[3]);
    *(ushort4*)&hb[(size_t)n * HC1 + C] = u;
  } else {
    float* hf = (float*)h1out;
    *(float4*)&hf[(size_t)n * HC1 + C] = *(float4*)r;
  }
}

// ---------------- linear2 ----------------
template<bool INBF>
__global__ __launch_bounds__(256) void linear2_kernel(
    const void* __restrict__ hin_, const float* __restrict__ Wl,
    const float* __restrict__ bl, const float* __restrict__ Wr,
    const float* __restrict__ br, float* __restrict__ xl, float* __restrict__ xr)
{
  __shared__ float xsT[HC1][16];   // 32KB
  int n0 = blockIdx.x * 16;
  int t = threadIdx.x;
  for (int r = 0; r < 8; r++) {
    int flat = (t + r * 256) * 4;
    int i = flat >> 9, k = flat & 511;
    float4 v;
    if (INBF) {
      const unsigned short* hb = (const unsigned short*)hin_;
      ushort4 u = *(const ushort4*)&hb[(size_t)(n0 + i) * HC1 + k];
      v.x = b2f(u.x); v.y = b2f(u.y); v.z = b2f(u.z); v.w = b2f(u.w);
    } else {
      const float* hf = (const float*)hin_;
      v = *(const float4*)&hf[(size_t)(n0 + i) * HC1 + k];
    }
    xsT[k + 0][i] = v.x; xsT[k + 1][i] = v.y; xsT[k + 2][i] = v.z; xsT[k + 3][i] = v.w;
  }
  __syncthreads();
  int m = t >> 7, j = t & 127;
  const float* W = m ? Wr : Wl;
  float bj = (m ? br : bl)[j];
  float* out = m ? xr : xl;
  float acc[16];
  #pragma unroll
  for (int i = 0; i < 16; i++) acc[i] = 0.f;
  for (int k = 0; k < HC1; k++) {
    float w = W[k * HID + j];
    float xv[16];
    *(float4*)&xv[0]  = *(const float4*)&xsT[k][0];
    *(float4*)&xv[4]  = *(const float4*)&xsT[k][4];
    *(float4*)&xv[8]  = *(const float4*)&xsT[k][8];
    *(float4*)&xv[12] = *(const float4*)&xsT[k][12];
    #pragma unroll
    for (int i = 0; i < 16; i++) acc[i] = fmaf(xv[i], w, acc[i]);
  }
  #pragma unroll
  for (int i = 0; i < 16; i++) out[(size_t)(n0 + i) * HID + j] = acc[i] + bj;
}

// ---------------- fused layer 2 (no head; eas-staged; chunk=8) ----------------
// block = 512 threads = 8 waves = 8 nodes. lane owns channels {lane, 64+lane}.
__global__ __launch_bounds__(512, 3) void fused2_kernel(
    const float* __restrict__ ea, const int* __restrict__ srcs,
    const float* __restrict__ We, const float* __restrict__ att,
    const float* __restrict__ xl, const float* __restrict__ xr,
    const float* __restrict__ bias, const int* __restrict__ offs,
    const int* __restrict__ csr, float* __restrict__ h2out)
{
  __shared__ float Ws[EDGE_DIM * HID];      // 16KB
  __shared__ float eas[8][8][EDGE_DIM];     // 8KB, per-wave chunk ea tile
  int t = threadIdx.x;
  for (int i = t * 4; i < EDGE_DIM * HID; i += 2048)
    *(float4*)&Ws[i] = *(const float4*)&We[i];
  __syncthreads();
  int wave = t >> 6, lane = t & 63;
  int n = blockIdx.x * 8 + wave;
  float ata = att[lane], atb = att[64 + lane];
  float xra = xr[(size_t)n * HID + lane], xrb = xr[(size_t)n * HID + 64 + lane];
  float oa = 0.f, ob = 0.f;
  float m = -3.0e38f, d = 0.f;
  int beg = offs[n], end = offs[n + 1];
  int ev = 0, sv = 0;
  if (lane < 8 && beg + lane < end) { ev = csr[beg + lane]; sv = srcs[ev]; }
  for (int i0 = beg; i0 < end; i0 += 8) {
    int nv = end - i0; if (nv > 8) nv = 8;
    int sarr[8];
    #pragma unroll
    for (int j = 0; j < 8; j++) sarr[j] = __shfl(sv, j);
    // stage this chunk's 8 ea rows into per-wave LDS (coalesced float4/lane)
    {
      int mye = __shfl(ev, lane >> 3);
      float4 eav = *(const float4*)&ea[(size_t)mye * EDGE_DIM + (lane & 7) * 4];
      *(float4*)&eas[wave][lane >> 3][(lane & 7) * 4] = eav;
    }
    // xl gathers issued before GEMM (latency hidden under FMA stream)
    float xa[8], xb[8];
    #pragma unroll
    for (int j = 0; j < 8; j++) {
      if (j < nv) {
        const float* p = &xl[(size_t)sarr[j] * HID];
        xa[j] = p[lane]; xb[j] = p[64 + lane];
      } else { xa[j] = 0.f; xb[j] = 0.f; }
    }
    // prefetch next chunk's indices
    if (lane < 8 && i0 + 8 + lane < end) { ev = csr[i0 + 8 + lane]; sv = srcs[ev]; }
    // ee-GEMM: LDS broadcast reads only
    float aa[8], ab[8];
    #pragma unroll
    for (int j = 0; j < 8; j++) { aa[j] = 0.f; ab[j] = 0.f; }
    #pragma unroll 2
    for (int kk = 0; kk < 8; kk++) {
      float av[8][4];
      #pragma unroll
      for (int j = 0; j < 8; j++)
        *(float4*)&av[j][0] = *(const float4*)&eas[wave][j][kk * 4];
      #pragma unroll
      for (int dk = 0; dk < 4; dk++) {
        float wA = Ws[(kk * 4 + dk) * HID + lane];
        float wB = Ws[(kk * 4 + dk) * HID + 64 + lane];
        #pragma unroll
        for (int j = 0; j < 8; j++) {
          aa[j] = fmaf(av[j][dk], wA, aa[j]);
          ab[j] = fmaf(av[j][dk], wB, ab[j]);
        }
      }
    }
    // logits: 8 independent 64-lane butterflies
    float pl[8];
    #pragma unroll
    for (int j = 0; j < 8; j++) {
      float za = aa[j] + xa[j] + xra;
      float zb = ab[j] + xb[j] + xrb;
      za = za > 0.f ? za : NEG_SLOPE * za;
      zb = zb > 0.f ? zb : NEG_SLOPE * zb;
      float s = za * ata + zb * atb;
      #pragma unroll
      for (int o = 1; o < 64; o <<= 1) s += __shfl_xor(s, o);
      pl[j] = (j < nv) ? s : -3.0e38f;
    }
    float cm = fmaxf(fmaxf(fmaxf(pl[0], pl[1]), fmaxf(pl[2], pl[3])),
                     fmaxf(fmaxf(pl[4], pl[5]), fmaxf(pl[6], pl[7])));
    float mn = fmaxf(m, cm);
    if (__any(mn > m + 8.f)) {
      float fs = __expf(m - mn);
      d *= fs; oa *= fs; ob *= fs;
      m = mn;
    }
    float p[8];
    #pragma unroll
    for (int j = 0; j < 8; j++) p[j] = __expf(pl[j] - m);
    d += ((p[0] + p[1]) + (p[2] + p[3])) + ((p[4] + p[5]) + (p[6] + p[7]));
    #pragma unroll
    for (int j = 0; j < 8; j++) {
      oa = fmaf(p[j], xa[j], oa);
      ob = fmaf(p[j], xb[j], ob);
    }
  }
  float invd = d > 0.f ? 1.f / d : 0.f;
  h2out[(size_t)n * HID + lane]      = oa * invd + bias[lane];
  h2out[(size_t)n * HID + 64 + lane] = ob * invd + bias[64 + lane];  // no relu after conv2
}

// ---------------- MLP head ----------------
__global__ __launch_bounds__(256) void head_kernel(
    const float* __restrict__ h2, const float* __restrict__ Wh1,
    const float* __restrict__ bh1, const float* __restrict__ Wh2,
    const float* __restrict__ bh2, float* __restrict__ out)
{
  __shared__ float hs[16][HID];   // 8KB
  __shared__ float ts[16][64];    // 4KB
  int n0 = blockIdx.x * 16;
  int t = threadIdx.x;
  for (int r = 0; r < 2; r++) {
    int flat = (t + r * 256) * 4; // 2048 floats
    int i = flat >> 7, k = flat & 127;
    *(float4*)&hs[i][k] = *(const float4*)&h2[(size_t)(n0 + i) * HID + k];
  }
  __syncthreads();
  int j = t & 63, g = t >> 6;
  float acc[4];
  #pragma unroll
  for (int q = 0; q < 4; q++) acc[q] = 0.f;
  for (int k = 0; k < HID; k++) {
    float w = Wh1[k * 64 + j];
    #pragma unroll
    for (int q = 0; q < 4; q++) acc[q] = fmaf(hs[g + 4 * q][k], w, acc[q]);
  }
  float bj = bh1[j];
  #pragma unroll
  for (int q = 0; q < 4; q++) {
    float v = acc[q] + bj;
    ts[g + 4 * q][j] = v > 0.f ? v : 0.f;
  }
  __syncthreads();
  if (t < 32) {
    int nl = t >> 1, k = t & 1;
    float acc2 = bh2[k];
    for (int jj = 0; jj < 64; jj++) acc2 = fmaf(ts[nl][jj], Wh2[jj * 2 + k], acc2);
    out[(size_t)(n0 + nl) * 2 + k] = acc2;
  }
}

extern "C" void kernel_launch(void* const* d_in, const int* in_sizes, int n_in,
                              void* d_out, int out_size, void* d_ws, size_t ws_size,
                              hipStream_t stream)
{
  (void)in_sizes; (void)n_in; (void)out_size;
  const float* x    = (const float*)d_in[0];
  const int* eidx   = (const int*)d_in[1];
  const float* ea   = (const float*)d_in[2];
  const float* Wl1  = (const float*)d_in[3];
  const float* bl1  = (const float*)d_in[4];
  const float* Wr1  = (const float*)d_in[5];
  const float* br1  = (const float*)d_in[6];
  const float* We1  = (const float*)d_in[7];
  const float* att1 = (const float*)d_in[8];
  const float* bias1= (const float*)d_in[9];
  const float* Wl2  = (const float*)d_in[10];
  const float* bl2  = (const float*)d_in[11];
  const float* Wr2  = (const float*)d_in[12];
  const float* br2  = (const float*)d_in[13];
  const float* We2  = (const float*)d_in[14];
  const float* att2 = (const float*)d_in[15];
  const float* bias2= (const float*)d_in[16];
  const float* Wh1  = (const float*)d_in[17];
  const float* bh1  = (const float*)d_in[18];
  const float* Wh2  = (const float*)d_in[19];
  const float* bh2  = (const float*)d_in[20];
  const int* srcs = eidx;
  const int* dsts = eidx + N_EDGES;
  float* out = (float*)d_out;

  const size_t szBig = (size_t)N_NODES * HC1 * sizeof(float);
  auto aln = [](size_t b) { return (b + 511) & ~(size_t)511; };
  size_t smallSz = aln((size_t)N_NODES * 4) * 3 + aln((size_t)(N_NODES + 1) * 4)
                 + aln((size_t)N_EDGES * 4) + aln(64 * 4) * 2;
  size_t needF = aln(szBig) * 3 + smallSz + 4096;
  bool useBF = ws_size < needF;

  char* p = (char*)d_ws;
  auto alloc = [&](size_t bytes) { char* q = p; p += (bytes + 511) & ~(size_t)511; return q; };
  float* xl1 = (float*)alloc(szBig);
  float* xr1 = (float*)alloc(szBig);          // reused for xl2/xr2 after fused1
  void*  h1  = (void*)alloc(useBF ? szBig / 2 : szBig);
  int* deg    = (int*)alloc((size_t)N_NODES * 4);
  int* offs   = (int*)alloc((size_t)(N_NODES + 1) * 4);
  int* cursor = (int*)alloc((size_t)N_NODES * 4);
  int* csr    = (int*)alloc((size_t)N_EDGES * 4);
  int* hist   = (int*)alloc(64 * 4);
  int* cursor2= (int*)alloc(64 * 4);
  int* perm   = (int*)alloc((size_t)N_NODES * 4);
  float* xl2 = xr1;
  float* xr2 = xr1 + (size_t)N_NODES * HID;
  float* h2  = xl1;                            // xl1 region dead after fused1

  hipLaunchKernelGGL(zero_deg_kernel, dim3((N_NODES + 255) / 256), dim3(256), 0, stream, deg, hist);
  hipLaunchKernelGGL(deg_count_kernel, dim3((N_EDGES + 255) / 256), dim3(256), 0, stream, dsts, deg);
  hipLaunchKernelGGL(hist_kernel, dim3((N_NODES + 255) / 256), dim3(256), 0, stream, deg, hist);
  hipLaunchKernelGGL(histscan_kernel, dim3(1), dim3(64), 0, stream, hist, cursor2);
  hipLaunchKernelGGL(permscatter_kernel, dim3((N_NODES + 255) / 256), dim3(256), 0, stream,
                     deg, cursor2, perm);
  hipLaunchKernelGGL(scan_kernel, dim3(1), dim3(1024), 0, stream, deg, offs, cursor);
  hipLaunchKernelGGL(scatter_kernel, dim3((N_EDGES + 255) / 256), dim3(256), 0, stream, dsts, cursor, csr);
  hipLaunchKernelGGL(linear1_kernel, dim3(N_NODES / 16), dim3(256), 0, stream,
                     x, Wl1, bl1, Wr1, br1, xl1, xr1);
  if (useBF)
    hipLaunchKernelGGL((fused1_kernel<true>), dim3(N_NODES / 8), dim3(1024), 0, stream,
                       ea, srcs, We1, att1, xl1, xr1, bias1, offs, csr, perm, h1);
  else
    hipLaunchKernelGGL((fused1_kernel<false>), dim3(N_NODES / 8), dim3(1024), 0, stream,
                       ea, srcs, We1, att1, xl1, xr1, bias1, offs, csr, perm, h1);
  if (useBF)
    hipLaunchKernelGGL((linear2_kernel<true>), dim3(N_NODES / 16), dim3(256), 0, stream,
                       h1, Wl2, bl2, Wr2, br2, xl2, xr2);
  else
    hipLaunchKernelGGL((linear2_kernel<false>), dim3(N_NODES / 16), dim3(256), 0, stream,
                       h1, Wl2, bl2, Wr2, br2, xl2, xr2);
  hipLaunchKernelGGL(fused2_kernel, dim3(N_NODES / 8), dim3(512), 0, stream,
                     ea, srcs, We2, att2, xl2, xr2, bias2, offs, csr, h2);
  hipLaunchKernelGGL(head_kernel, dim3(N_NODES / 16), dim3(256), 0, stream,
                     h2, Wh1, bh1, Wh2, bh2, out);
}